// Round 2
// baseline (222.427 us; speedup 1.0000x reference)
//
#include <hip/hip_runtime.h>
#include <math.h>

#define B_   32
#define T_   8192
#define RNN_ 1024
#define ENC_ 512
#define ATT_ 128
#define LOC_ 32
#define K_   31
#define PAD_ 15

__device__ __forceinline__ float fast_tanh(float x) {
    x = fminf(15.f, fmaxf(-15.f, x));
    float e = __expf(2.f * x);
    return (e - 1.f) * __builtin_amdgcn_rcpf(e + 1.f);
}

__device__ __forceinline__ float fast_sigmoid(float x) {
    x = fminf(30.f, fmaxf(-30.f, x));
    float e = __expf(-x);
    return __builtin_amdgcn_rcpf(1.f + e);
}

// ---------------- Kernel A: fused weight-prep + query GEMV ----------------
// blocks 0..1023: q[b,a] = queries[b,:] . w_query[a,:]   (one wave per (b,a))
// block 1024:     transpose conv weights [LOC,2,K] -> [K][2][LOC]
__global__ __launch_bounds__(256) void k_prep_query(const float* __restrict__ queries,
                                                    const float* __restrict__ wq,
                                                    const float* __restrict__ wconv,
                                                    float* __restrict__ qout,
                                                    float* __restrict__ wT) {
    if (blockIdx.x == (B_ * ATT_) / 4) {
        for (int i = threadIdx.x; i < LOC_ * 2 * K_; i += blockDim.x) {
            int l = i / (2 * K_);
            int rem = i % (2 * K_);
            int c = rem / K_;
            int k = rem % K_;
            wT[k * (2 * LOC_) + c * LOC_ + l] = wconv[i];
        }
        return;
    }
    int w    = blockIdx.x * 4 + (threadIdx.x >> 6);
    int lane = threadIdx.x & 63;
    int b = w >> 7, a = w & 127;
    const float4* qrow = (const float4*)(queries + (size_t)b * RNN_);
    const float4* wrow = (const float4*)(wq + (size_t)a * RNN_);
    float acc = 0.f;
#pragma unroll
    for (int i = 0; i < 4; ++i) {
        float4 x = qrow[i * 64 + lane];
        float4 y = wrow[i * 64 + lane];
        acc += x.x * y.x + x.y * y.y + x.z * y.z + x.w * y.w;
    }
#pragma unroll
    for (int off = 32; off; off >>= 1) acc += __shfl_xor(acc, off);
    if (lane == 0) qout[b * ATT_ + a] = acc;
}

// ---------------- Kernel B: fused conv + 1x1 + tanh + score + sigmoid ------------
#define VT    2
#define BLK2  256
#define TILE2 (BLK2 * VT)  // 512 t's per block

__global__ __launch_bounds__(256) void k_score(
    const float* __restrict__ pm,          // [B,ATT,T]
    const float* __restrict__ prev,        // [B,T]
    const float* __restrict__ cum,         // [B,T]
    const unsigned char* __restrict__ masks,
    const float* __restrict__ qbuf,        // [B,ATT]
    const float* __restrict__ wT,          // [K][2][LOC]
    const float* __restrict__ w1,          // [ATT,LOC]
    const float* __restrict__ wsc,         // [ATT]
    float* __restrict__ pout)              // [B,T]
{
    __shared__ float sP[TILE2 + K_ - 1];
    __shared__ float sC[TILE2 + K_ - 1];
    int blk  = blockIdx.x;
    int b    = blk >> 4;       // 16 tiles of 512 per row of 8192
    int tile = blk & 15;
    int tbase = tile * TILE2;
    const float* prow = prev + (size_t)b * T_;
    const float* crow = cum + (size_t)b * T_;
    for (int i = threadIdx.x; i < TILE2 + K_ - 1; i += BLK2) {
        int g = tbase - PAD_ + i;
        bool ok = (g >= 0) && (g < T_);
        sP[i] = ok ? prow[g] : 0.f;
        sC[i] = ok ? crow[g] : 0.f;
    }
    __syncthreads();

    int lt = threadIdx.x * VT;
    int t0 = tbase + lt;

    float loc[LOC_][VT];
#pragma unroll
    for (int l = 0; l < LOC_; ++l)
#pragma unroll
        for (int j = 0; j < VT; ++j) loc[l][j] = 0.f;

    for (int k = 0; k < K_; ++k) {
        float pv[VT], cv[VT];
#pragma unroll
        for (int j = 0; j < VT; ++j) {
            pv[j] = sP[lt + k + j];
            cv[j] = sC[lt + k + j];
        }
        const float* wk = wT + k * (2 * LOC_);
#pragma unroll
        for (int l = 0; l < LOC_; ++l) {
            float wp = wk[l];
            float wc = wk[LOC_ + l];
#pragma unroll
            for (int j = 0; j < VT; ++j)
                loc[l][j] = fmaf(wp, pv[j], fmaf(wc, cv[j], loc[l][j]));
        }
    }

    float score0 = 0.f, score1 = 0.f;
    const float* pmb = pm + (size_t)b * ATT_ * T_ + t0;
    const float* qb  = qbuf + b * ATT_;
    for (int a = 0; a < ATT_; ++a) {
        float q   = qb[a];
        float wsa = wsc[a];
        const float* w1a = w1 + a * LOC_;
        float2 pmv = *(const float2*)(pmb + (size_t)a * T_);
        float l20 = 0.f, l21 = 0.f;
#pragma unroll
        for (int l = 0; l < LOC_; ++l) {
            float wv = w1a[l];
            l20 = fmaf(wv, loc[l][0], l20);
            l21 = fmaf(wv, loc[l][1], l21);
        }
        score0 += wsa * fast_tanh(q + pmv.x + l20);
        score1 += wsa * fast_tanh(q + pmv.y + l21);
    }

    unsigned char m0 = masks[(size_t)b * T_ + t0];
    unsigned char m1 = masks[(size_t)b * T_ + t0 + 1];
    float s0 = m0 ? -3.0e38f : score0;
    float s1 = m1 ? -3.0e38f : score1;
    float2 out;
    out.x = fast_sigmoid(s0);
    out.y = fast_sigmoid(s1);
    *(float2*)(pout + (size_t)b * T_ + t0) = out;
}

// ---------------- Kernel C: fused align + context partials ----------------
// grid: 32 b x 16 tiles of 512 t. Phase 1: align tile -> d_out + LDS.
// Phase 2: each wave handles 128 channels; align tile cached in 8 VGPR/lane;
//          partial ctx per (b,c,tile) -> ws (deterministic, no atomics).
#define TILE3 512
__global__ __launch_bounds__(256) void k_align_ctx(
    const float* __restrict__ p,       // [B,T] (ws)
    const float* __restrict__ prev,    // [B,T]
    const float* __restrict__ mem,     // [B,ENC,T]
    float* __restrict__ align_out,     // [B,T] (d_out tail)
    float* __restrict__ part)          // [B*ENC][16]
{
    __shared__ float sA[TILE3];
    int blk  = blockIdx.x;
    int b    = blk >> 4;
    int tile = blk & 15;
    int tbase = tile * TILE3;
    const float* pr = p + (size_t)b * T_;
    const float* vr = prev + (size_t)b * T_;

    int lt = threadIdx.x * 2;
    int t0 = tbase + lt;
    float2 p2 = *(const float2*)(pr + t0);
    float2 v2 = *(const float2*)(vr + t0);
    float pm1 = (t0 > 0) ? pr[t0 - 1] : 0.f;
    float vm1 = (t0 > 0) ? vr[t0 - 1] : 0.f;
    float a0 = v2.x * p2.x + vm1 * (1.f - pm1);
    float a1 = v2.y * p2.y + v2.x * (1.f - p2.x);
    sA[lt] = a0;
    sA[lt + 1] = a1;
    float2 ao; ao.x = a0; ao.y = a1;
    *(float2*)(align_out + (size_t)b * T_ + t0) = ao;
    __syncthreads();

    int wv   = threadIdx.x >> 6;
    int lane = threadIdx.x & 63;
    // cache this lane's align slots: floats [4*lane .. 4*lane+3] and [256+4*lane ..]
    float av[8];
#pragma unroll
    for (int j = 0; j < 4; ++j) {
        av[j]     = sA[4 * lane + j];
        av[4 + j] = sA[256 + 4 * lane + j];
    }
    const float* mb = mem + ((size_t)b * ENC_) * T_ + tbase;

#pragma unroll 4
    for (int cc = 0; cc < 128; ++cc) {
        int c = wv * 128 + cc;
        const float4* mrow = (const float4*)(mb + (size_t)c * T_);
        float4 m0 = mrow[lane];
        float4 m1 = mrow[64 + lane];
        float acc = m0.x * av[0] + m0.y * av[1] + m0.z * av[2] + m0.w * av[3]
                  + m1.x * av[4] + m1.y * av[5] + m1.z * av[6] + m1.w * av[7];
#pragma unroll
        for (int off = 32; off; off >>= 1) acc += __shfl_xor(acc, off);
        if (lane == 0) part[((size_t)b * ENC_ + c) * 16 + tile] = acc;
    }
}

// ---------------- Kernel D: reduce partials -> contexts ----------------
__global__ __launch_bounds__(256) void k_reduce(const float* __restrict__ part,
                                                float* __restrict__ ctx) {
    int idx = blockIdx.x * blockDim.x + threadIdx.x;  // 0 .. B*ENC-1
    const float4* pr = (const float4*)(part + (size_t)idx * 16);
    float4 a = pr[0], b = pr[1], c = pr[2], d = pr[3];
    float s = a.x + a.y + a.z + a.w + b.x + b.y + b.z + b.w
            + c.x + c.y + c.z + c.w + d.x + d.y + d.z + d.w;
    ctx[idx] = s;
}

extern "C" void kernel_launch(void* const* d_in, const int* in_sizes, int n_in,
                              void* d_out, int out_size, void* d_ws, size_t ws_size,
                              hipStream_t stream) {
    const float* queries = (const float*)d_in[0];
    const float* memories = (const float*)d_in[1];
    const float* pm = (const float*)d_in[2];
    const float* prev = (const float*)d_in[3];
    const float* cum = (const float*)d_in[4];
    const unsigned char* masks = (const unsigned char*)d_in[5];
    const float* w_query = (const float*)d_in[6];
    const float* w_conv = (const float*)d_in[7];
    const float* w_1x1 = (const float*)d_in[8];
    const float* w_score = (const float*)d_in[9];

    float* out_ctx = (float*)d_out;                       // [B,ENC]
    float* out_align = (float*)d_out + (size_t)B_ * ENC_; // [B,T]

    float* ws_q = (float*)d_ws;                       // B*ATT = 4096
    float* ws_p = ws_q + B_ * ATT_;                   // B*T = 262144
    float* ws_wT = ws_p + (size_t)B_ * T_;            // K*2*LOC = 1984
    float* ws_part = ws_wT + 1984;                    // B*ENC*16 = 262144 (16B-aligned)

    hipLaunchKernelGGL(k_prep_query, dim3((B_ * ATT_) / 4 + 1), dim3(256), 0, stream,
                       queries, w_query, w_conv, ws_q, ws_wT);
    hipLaunchKernelGGL(k_score, dim3(B_ * (T_ / TILE2)), dim3(BLK2), 0, stream,
                       pm, prev, cum, masks, ws_q, ws_wT, w_1x1, w_score, ws_p);
    hipLaunchKernelGGL(k_align_ctx, dim3(B_ * (T_ / TILE3)), dim3(256), 0, stream,
                       ws_p, prev, memories, out_align, ws_part);
    hipLaunchKernelGGL(k_reduce, dim3((B_ * ENC_) / 256), dim3(256), 0, stream,
                       ws_part, out_ctx);
}

// Round 3
// 191.179 us; speedup vs baseline: 1.1634x; 1.1634x over previous
//
#include <hip/hip_runtime.h>
#include <math.h>

#define B_   32
#define T_   8192
#define RNN_ 1024
#define ENC_ 512
#define ATT_ 128
#define LOC_ 32
#define K_   31
#define PAD_ 15

__device__ __forceinline__ float fast_tanh(float x) {
    x = fminf(15.f, fmaxf(-15.f, x));
    float e = __expf(2.f * x);
    return (e - 1.f) * __builtin_amdgcn_rcpf(e + 1.f);
}

__device__ __forceinline__ float fast_sigmoid(float x) {
    x = fminf(30.f, fmaxf(-30.f, x));
    float e = __expf(-x);
    return __builtin_amdgcn_rcpf(1.f + e);
}

// ---------------- Kernel A: fused weight-prep + query GEMV ----------------
__global__ __launch_bounds__(256) void k_prep_query(const float* __restrict__ queries,
                                                    const float* __restrict__ wq,
                                                    const float* __restrict__ wconv,
                                                    float* __restrict__ qout,
                                                    float* __restrict__ wT) {
    if (blockIdx.x == (B_ * ATT_) / 4) {
        for (int i = threadIdx.x; i < LOC_ * 2 * K_; i += blockDim.x) {
            int l = i / (2 * K_);
            int rem = i % (2 * K_);
            int c = rem / K_;
            int k = rem % K_;
            wT[k * (2 * LOC_) + c * LOC_ + l] = wconv[i];
        }
        return;
    }
    int w    = blockIdx.x * 4 + (threadIdx.x >> 6);
    int lane = threadIdx.x & 63;
    int b = w >> 7, a = w & 127;
    const float4* qrow = (const float4*)(queries + (size_t)b * RNN_);
    const float4* wrow = (const float4*)(wq + (size_t)a * RNN_);
    float acc = 0.f;
#pragma unroll
    for (int i = 0; i < 4; ++i) {
        float4 x = qrow[i * 64 + lane];
        float4 y = wrow[i * 64 + lane];
        acc += x.x * y.x + x.y * y.y + x.z * y.z + x.w * y.w;
    }
#pragma unroll
    for (int off = 32; off; off >>= 1) acc += __shfl_xor(acc, off);
    if (lane == 0) qout[b * ATT_ + a] = acc;
}

// ---------------- Kernel B: fused conv + 1x1 + tanh + score + sigmoid ------------
#define VT    2
#define BLK2  256
#define TILE2 (BLK2 * VT)  // 512 t's per block

__global__ __launch_bounds__(256) void k_score(
    const float* __restrict__ pm,          // [B,ATT,T]
    const float* __restrict__ prev,        // [B,T]
    const float* __restrict__ cum,         // [B,T]
    const unsigned char* __restrict__ masks,
    const float* __restrict__ qbuf,        // [B,ATT]
    const float* __restrict__ wT,          // [K][2][LOC]
    const float* __restrict__ w1,          // [ATT,LOC]
    const float* __restrict__ wsc,         // [ATT]
    float* __restrict__ pout)              // [B,T]
{
    __shared__ float sP[TILE2 + K_ - 1];
    __shared__ float sC[TILE2 + K_ - 1];
    int blk  = blockIdx.x;
    int b    = blk >> 4;
    int tile = blk & 15;
    int tbase = tile * TILE2;
    const float* prow = prev + (size_t)b * T_;
    const float* crow = cum + (size_t)b * T_;
    for (int i = threadIdx.x; i < TILE2 + K_ - 1; i += BLK2) {
        int g = tbase - PAD_ + i;
        bool ok = (g >= 0) && (g < T_);
        sP[i] = ok ? prow[g] : 0.f;
        sC[i] = ok ? crow[g] : 0.f;
    }
    __syncthreads();

    int lt = threadIdx.x * VT;
    int t0 = tbase + lt;

    float loc[LOC_][VT];
#pragma unroll
    for (int l = 0; l < LOC_; ++l)
#pragma unroll
        for (int j = 0; j < VT; ++j) loc[l][j] = 0.f;

    for (int k = 0; k < K_; ++k) {
        float pv[VT], cv[VT];
#pragma unroll
        for (int j = 0; j < VT; ++j) {
            pv[j] = sP[lt + k + j];
            cv[j] = sC[lt + k + j];
        }
        const float* wk = wT + k * (2 * LOC_);
#pragma unroll
        for (int l = 0; l < LOC_; ++l) {
            float wp = wk[l];
            float wc = wk[LOC_ + l];
#pragma unroll
            for (int j = 0; j < VT; ++j)
                loc[l][j] = fmaf(wp, pv[j], fmaf(wc, cv[j], loc[l][j]));
        }
    }

    float score0 = 0.f, score1 = 0.f;
    const float* pmb = pm + (size_t)b * ATT_ * T_ + t0;
    const float* qb  = qbuf + b * ATT_;
    for (int a = 0; a < ATT_; ++a) {
        float q   = qb[a];
        float wsa = wsc[a];
        const float* w1a = w1 + a * LOC_;
        float2 pmv = *(const float2*)(pmb + (size_t)a * T_);
        float l20 = 0.f, l21 = 0.f;
#pragma unroll
        for (int l = 0; l < LOC_; ++l) {
            float wv = w1a[l];
            l20 = fmaf(wv, loc[l][0], l20);
            l21 = fmaf(wv, loc[l][1], l21);
        }
        score0 += wsa * fast_tanh(q + pmv.x + l20);
        score1 += wsa * fast_tanh(q + pmv.y + l21);
    }

    unsigned char m0 = masks[(size_t)b * T_ + t0];
    unsigned char m1 = masks[(size_t)b * T_ + t0 + 1];
    float s0 = m0 ? -3.0e38f : score0;
    float s1 = m1 ? -3.0e38f : score1;
    float2 out;
    out.x = fast_sigmoid(s0);
    out.y = fast_sigmoid(s1);
    *(float2*)(pout + (size_t)b * T_ + t0) = out;
}

// ---------------- Kernel C: alignments = prev*p + shift(prev*(1-p)) --------------
__global__ __launch_bounds__(256) void k_align(const float* __restrict__ p,
                                               const float* __restrict__ prev,
                                               float* __restrict__ align) {
    int idx = blockIdx.x * blockDim.x + threadIdx.x;
    int b  = idx / (T_ / 4);
    int t0 = (idx % (T_ / 4)) * 4;
    const float* pr = p + (size_t)b * T_;
    const float* vr = prev + (size_t)b * T_;
    float4 p4 = *(const float4*)(pr + t0);
    float4 v4 = *(const float4*)(vr + t0);
    float pm1 = (t0 > 0) ? pr[t0 - 1] : 0.f;
    float vm1 = (t0 > 0) ? vr[t0 - 1] : 0.f;
    float4 o;
    o.x = v4.x * p4.x + vm1 * (1.f - pm1);
    o.y = v4.y * p4.y + v4.x * (1.f - p4.x);
    o.z = v4.z * p4.z + v4.y * (1.f - p4.y);
    o.w = v4.w * p4.w + v4.z * (1.f - p4.z);
    *(float4*)(align + (size_t)b * T_ + t0) = o;
}

// ---------------- Kernel D: contexts[b,c] = sum_t align[b,t]*mem[b,c,t] ----------
// One wave per (b,c) row: 32 KB contiguous stream, unroll 8 (16 float4 in
// flight), dual accumulators to shorten the dependent add chain.
__global__ __launch_bounds__(256) void k_context(const float* __restrict__ mem,
                                                 const float* __restrict__ align,
                                                 float* __restrict__ ctx) {
    int w    = blockIdx.x * 4 + (threadIdx.x >> 6);
    int lane = threadIdx.x & 63;
    int b = w >> 9;   // /512
    int c = w & 511;
    const float4* mrow = (const float4*)(mem + ((size_t)b * ENC_ + c) * T_);
    const float4* arow = (const float4*)(align + (size_t)b * T_);
    float acc0 = 0.f, acc1 = 0.f;
#pragma unroll 8
    for (int i = 0; i < T_ / 256; ++i) {  // 32 iters, 16B/lane each
        float4 m = mrow[i * 64 + lane];
        float4 a = arow[i * 64 + lane];
        if (i & 1)
            acc1 += m.x * a.x + m.y * a.y + m.z * a.z + m.w * a.w;
        else
            acc0 += m.x * a.x + m.y * a.y + m.z * a.z + m.w * a.w;
    }
    float acc = acc0 + acc1;
#pragma unroll
    for (int off = 32; off; off >>= 1) acc += __shfl_xor(acc, off);
    if (lane == 0) ctx[b * ENC_ + c] = acc;
}

extern "C" void kernel_launch(void* const* d_in, const int* in_sizes, int n_in,
                              void* d_out, int out_size, void* d_ws, size_t ws_size,
                              hipStream_t stream) {
    const float* queries = (const float*)d_in[0];
    const float* memories = (const float*)d_in[1];
    const float* pm = (const float*)d_in[2];
    const float* prev = (const float*)d_in[3];
    const float* cum = (const float*)d_in[4];
    const unsigned char* masks = (const unsigned char*)d_in[5];
    const float* w_query = (const float*)d_in[6];
    const float* w_conv = (const float*)d_in[7];
    const float* w_1x1 = (const float*)d_in[8];
    const float* w_score = (const float*)d_in[9];

    float* out_ctx = (float*)d_out;                       // [B,ENC]
    float* out_align = (float*)d_out + (size_t)B_ * ENC_; // [B,T]

    float* ws_q = (float*)d_ws;                       // B*ATT
    float* ws_p = ws_q + B_ * ATT_;                   // B*T
    float* ws_wT = ws_p + (size_t)B_ * T_;            // K*2*LOC

    hipLaunchKernelGGL(k_prep_query, dim3((B_ * ATT_) / 4 + 1), dim3(256), 0, stream,
                       queries, w_query, w_conv, ws_q, ws_wT);
    hipLaunchKernelGGL(k_score, dim3(B_ * (T_ / TILE2)), dim3(BLK2), 0, stream,
                       pm, prev, cum, masks, ws_q, ws_wT, w_1x1, w_score, ws_p);
    hipLaunchKernelGGL(k_align, dim3((B_ * T_ / 4) / 256), dim3(256), 0, stream,
                       ws_p, prev, out_align);
    hipLaunchKernelGGL(k_context, dim3((B_ * ENC_) / 4), dim3(256), 0, stream,
                       memories, out_align, out_ctx);
}